// Round 8
// baseline (1120.163 us; speedup 1.0000x reference)
//
#include <hip/hip_runtime.h>
#include <hip/hip_bf16.h>
#include <math.h>

// Problem: input (16,1024,512) f32, codebook (8192,512) f32
#define N_ROWS 16384
#define DIM    512
#define VOCAB  8192

typedef __attribute__((ext_vector_type(8))) short short8;
typedef __attribute__((ext_vector_type(4))) float f32x4;

__device__ inline unsigned short f2bf(float f) {      // RNE f32 -> bf16 bits
    unsigned u = __float_as_uint(f);
    u += 0x7fff + ((u >> 16) & 1);
    return (unsigned short)(u >> 16);
}

__device__ inline void gload16(const void* g, void* l) {
    __builtin_amdgcn_global_load_lds(
        (const __attribute__((address_space(1))) void*)g,
        (__attribute__((address_space(3))) void*)l, 16, 0, 0);
}

// swizzled LDS fragment read: row rh (128B pitch), 16B slot, slot ^= rh&7
__device__ inline short8 frag(const char* base, int rh, int slot) {
    return *(const short8*)(base + rh * 128 + (((slot) ^ (rh & 7)) << 4));
}

__device__ inline void top2_ins(float s, int v, float& s1, int& i1, float& s2, int& i2) {
    if (s < s1 || (s == s1 && v < i1)) { s2 = s1; i2 = i1; s1 = s; i1 = v; }
    else if (s < s2 || (s == s2 && v < i2)) { s2 = s; i2 = v; }
}

// ---------------------------------------------------------------------------
// fp32 -> bf16 for input x
// ---------------------------------------------------------------------------
__global__ void k_split_hi(const float* __restrict__ in, unsigned short* __restrict__ hi,
                           int n4) {
    int t = blockIdx.x * 256 + threadIdx.x;
    if (t >= n4) return;
    float4 v = reinterpret_cast<const float4*>(in)[t];
    ushort4 h;
    h.x = f2bf(v.x); h.y = f2bf(v.y); h.z = f2bf(v.z); h.w = f2bf(v.w);
    reinterpret_cast<ushort4*>(hi)[t] = h;
}

// ---------------------------------------------------------------------------
// codebook: fp32 -> bf16 AND c2[v] = sum(cb[v]^2) in one pass (validated r6/r7)
// ---------------------------------------------------------------------------
__global__ void k_split_cb(const float* __restrict__ cb, unsigned short* __restrict__ hi,
                           float* __restrict__ c2) {
    int row  = blockIdx.x * 4 + (threadIdx.x >> 6);
    int lane = threadIdx.x & 63;
    const float4* p = reinterpret_cast<const float4*>(cb + (size_t)row * DIM);
    float4 a = p[lane * 2], b = p[lane * 2 + 1];
    float s = a.x*a.x + a.y*a.y + a.z*a.z + a.w*a.w
            + b.x*b.x + b.y*b.y + b.z*b.z + b.w*b.w;
    short8 h;
    h[0] = f2bf(a.x); h[1] = f2bf(a.y); h[2] = f2bf(a.z); h[3] = f2bf(a.w);
    h[4] = f2bf(b.x); h[5] = f2bf(b.y); h[6] = f2bf(b.z); h[7] = f2bf(b.w);
    *reinterpret_cast<short8*>(hi + (size_t)row * DIM + lane * 8) = h;
#pragma unroll
    for (int off = 32; off > 0; off >>= 1) s += __shfl_xor(s, off, 64);
    if (lane == 0) c2[row] = s;
}

// ---------------------------------------------------------------------------
// 8-phase 256x256 bf16 MFMA GEMM (K = 512) with fused per-128-col top-2
// argmin epilogue. 8 waves (2Mx4N interleaved), BK=64, 128 KiB LDS
// (2 dbuf x (A,B) x 2 halves x [128][64] bf16, XOR slot swizzle), counted
// vmcnt(4) at P4/P8 only. This is the r3 kernel (validated correct) with the
// register fix: launch_bounds(512,1) -> 256-reg budget (r3's (512,2) capped
// at 128 and spilled acc to scratch: WRITE_SIZE 2.1 GB, MfmaUtil 8%).
// ---------------------------------------------------------------------------
#define LDSA(b, h) (As + (b) * 32768 + (h) * 16384)
#define LDSB(b, h) (Bs + (b) * 32768 + (h) * 16384)

#define READ_A(BUF, H) do { const char* _b = LDSA(BUF, H);                  \
    _Pragma("unroll") for (int m = 0; m < 4; ++m)                           \
    _Pragma("unroll") for (int kk = 0; kk < 2; ++kk)                        \
        af[m][kk] = frag(_b, m * 32 + arow, kk * 4 + lg); } while (0)

#define READ_B0(BUF) do { const char* _b = LDSB(BUF, 0);                    \
    _Pragma("unroll") for (int n = 0; n < 2; ++n)                           \
    _Pragma("unroll") for (int kk = 0; kk < 2; ++kk)                        \
        bf0[n][kk] = frag(_b, n * 64 + brow, kk * 4 + lg); } while (0)

#define READ_B1(BUF) do { const char* _b = LDSB(BUF, 1);                    \
    _Pragma("unroll") for (int n = 0; n < 2; ++n)                           \
    _Pragma("unroll") for (int kk = 0; kk < 2; ++kk)                        \
        bf1[n][kk] = frag(_b, n * 64 + brow, kk * 4 + lg); } while (0)

#define STAGE_A2(BUF, H, T) do {                                            \
    const char* _s = (const char*)xhi +                                     \
        (rowBase + (H) * 128 + sgrow) * 1024 + ((T) << 7) + sgoff;          \
    char* _d = LDSA(BUF, H) + sgdst;                                        \
    gload16(_s, _d); gload16(_s + 65536, _d + 8192); } while (0)

#define STAGE_B2(BUF, H, T) do {                                            \
    const char* _s = (const char*)cbhi +                                    \
        (colBase + (H) * 128 + sgrow) * 1024 + ((T) << 7) + sgoff;          \
    char* _d = LDSB(BUF, H) + sgdst;                                        \
    gload16(_s, _d); gload16(_s + 8192 * 8, _d + 8192); } while (0)

#define SCHEDB __builtin_amdgcn_sched_barrier(0)
#define BARX   __builtin_amdgcn_s_barrier()
#define VMC4   asm volatile("s_waitcnt vmcnt(4)" ::: "memory")
#define VMC0   asm volatile("s_waitcnt vmcnt(0)" ::: "memory")

#define PHASE_TAIL(MB, BSET, NB) do {                                       \
    BARX;                                                                   \
    asm volatile("s_waitcnt lgkmcnt(0)" ::: "memory"); SCHEDB;              \
    __builtin_amdgcn_s_setprio(1);                                          \
    _Pragma("unroll") for (int kk = 0; kk < 2; ++kk)                        \
    _Pragma("unroll") for (int m = 0; m < 4; ++m)                           \
    _Pragma("unroll") for (int n = 0; n < 2; ++n)                           \
        acc[(MB) * 4 + m][(NB) * 2 + n] =                                   \
            __builtin_amdgcn_mfma_f32_16x16x32_bf16(                        \
                af[m][kk], BSET[n][kk], acc[(MB) * 4 + m][(NB) * 2 + n],    \
                0, 0, 0);                                                   \
    __builtin_amdgcn_s_setprio(0); SCHEDB;                                  \
    BARX; } while (0)

__launch_bounds__(512, 1)
__global__ void k_mfma8(const unsigned short* __restrict__ xhi,
                        const unsigned short* __restrict__ cbhi,
                        const float* __restrict__ c2,
                        float4* __restrict__ part) {
    __shared__ __align__(16) char Lds[131072];
    char* As = Lds;            // [buf][half][128 rows][64 bf16], slot^=(row&7)
    char* Bs = Lds + 65536;

    const int tid  = threadIdx.x;
    const int w8   = tid >> 6;
    const int wm   = w8 >> 2, wn = w8 & 3;
    const int lane = tid & 63, l15 = lane & 15, lg = lane >> 4;
    const int arow = wm * 16 + l15;
    const int brow = wn * 16 + l15;
    const int sgrow = 8 * w8 + (lane >> 3);
    const int sgoff = ((lane & 7) ^ (lane >> 3)) << 4;
    const int sgdst = w8 * 1024;

    // XCD-aware swizzle: grid 2048 = 64 row-tiles x 32 col-tiles (2048%8==0)
    const int g  = blockIdx.x;
    const int wg = (g & 7) * 256 + (g >> 3);
    const int by = wg >> 5, bx = wg & 31;
    const size_t rowBase = (size_t)by * 256;
    const size_t colBase = (size_t)bx * 256;

    f32x4 acc[8][4];
#pragma unroll
    for (int m = 0; m < 8; ++m)
#pragma unroll
        for (int n = 0; n < 4; ++n) acc[m][n] = (f32x4)0.f;
    short8 af[4][2], bf0[2][2], bf1[2][2];

    // Prologue: tile0 -> buf0 all 4 halves; tile1 -> buf1 {Ah0,Bh0}
    STAGE_A2(0, 0, 0); STAGE_B2(0, 0, 0);
    STAGE_A2(0, 1, 0); STAGE_B2(0, 1, 0);
    STAGE_A2(1, 0, 1); STAGE_B2(1, 0, 1);
    VMC4;
    BARX;

    for (int i = 0; i < 4; ++i) {               // 8 K-tiles of 64, 2 per iter
        const bool more = (i < 3);
        const int t1 = 2 * i + 1, t2 = 2 * i + 2, t3 = 2 * i + 3;
        // P1: quadrant (m0,n0) of buf0
        READ_A(0, 0); READ_B0(0);
        STAGE_A2(1, 1, t1);
        PHASE_TAIL(0, bf0, 0);
        // P2: (m0,n1)
        READ_B1(0);
        STAGE_B2(1, 1, t1);
        PHASE_TAIL(0, bf1, 1);
        // P3: (m1,n1)
        READ_A(0, 1);
        if (more) STAGE_A2(0, 0, t2);
        PHASE_TAIL(1, bf1, 1);
        // P4: (m1,n0) — reg-only MFMA; counted vmcnt
        if (more) { STAGE_B2(0, 0, t2); VMC4; } else { VMC0; }
        PHASE_TAIL(1, bf0, 0);
        // P5: (m0,n0) of buf1
        READ_A(1, 0); READ_B0(1);
        if (more) STAGE_A2(0, 1, t2);
        PHASE_TAIL(0, bf0, 0);
        // P6: (m0,n1)
        READ_B1(1);
        if (more) STAGE_B2(0, 1, t2);
        PHASE_TAIL(0, bf1, 1);
        // P7: (m1,n1)
        READ_A(1, 1);
        if (more) STAGE_A2(1, 0, t3);
        PHASE_TAIL(1, bf1, 1);
        // P8: (m1,n0)
        if (more) { STAGE_B2(1, 0, t3); VMC4; }
        PHASE_TAIL(1, bf0, 0);
    }

    // Epilogue: score = c2 - 2*acc; top-2 per row per 128-col half.
    // C frag: col = l15, row = 4*lg + reg. Per-wave rows mf*32+wm*16+4lg+reg.
    float c2v[4];
#pragma unroll
    for (int nf = 0; nf < 4; ++nf) c2v[nf] = c2[colBase + nf * 64 + wn * 16 + l15];

    float4* scr = (float4*)Lds;   // [256 rows][8 = wn*2+h], reuse of staging LDS
#pragma unroll
    for (int mf = 0; mf < 8; ++mf) {
#pragma unroll
        for (int r = 0; r < 4; ++r) {
#pragma unroll
            for (int h = 0; h < 2; ++h) {
                float s1 = INFINITY, s2 = INFINITY;
                int   i1 = 0x7fffffff, i2 = 0x7fffffff;
#pragma unroll
                for (int n = 0; n < 2; ++n) {
                    int nf = h * 2 + n;
                    float s = fmaf(-2.f, acc[mf][nf][r], c2v[nf]);
                    int  vv = (int)colBase + nf * 64 + wn * 16 + l15;
                    top2_ins(s, vv, s1, i1, s2, i2);
                }
#pragma unroll
                for (int off = 1; off < 16; off <<= 1) {
                    float t1 = __shfl_xor(s1, off, 64); int j1 = __shfl_xor(i1, off, 64);
                    float t2 = __shfl_xor(s2, off, 64); int j2 = __shfl_xor(i2, off, 64);
                    bool bfirst = (t1 < s1) || (t1 == s1 && j1 < i1);
                    if (bfirst) {
                        float ns; int ni;
                        if (s1 < t2 || (s1 == t2 && i1 < j2)) { ns = s1; ni = i1; }
                        else                                   { ns = t2; ni = j2; }
                        s1 = t1; i1 = j1; s2 = ns; i2 = ni;
                    } else if (t1 < s2 || (t1 == s2 && j1 < i2)) { s2 = t1; i2 = j1; }
                }
                if (l15 == 0)
                    scr[(mf * 32 + wm * 16 + 4 * lg + r) * 8 + wn * 2 + h] =
                        make_float4(s1, __int_as_float(i1), s2, __int_as_float(i2));
            }
        }
    }
    __syncthreads();
    {   // 512 threads: row = tid>>1, half = tid&1 -> merge 4 wn entries
        int row = tid >> 1, h = tid & 1;
        float s1 = INFINITY, s2 = INFINITY;
        int   i1 = 0x7fffffff, i2 = 0x7fffffff;
#pragma unroll
        for (int q = 0; q < 4; ++q) {
            float4 p = scr[row * 8 + q * 2 + h];
            top2_ins(p.x, __float_as_int(p.y), s1, i1, s2, i2);
            top2_ins(p.z, __float_as_int(p.w), s1, i1, s2, i2);
        }
        part[(rowBase + row) * 64 + bx * 2 + h] =
            make_float4(s1, __int_as_float(i1), s2, __int_as_float(i2));
    }
}

// ---------------------------------------------------------------------------
// Per-row final: approx global min over 64 per-128-col top2s; exact fp32
// rescore of all candidates within min+1.0 (>14 sigma of bf16 approx error).
// ---------------------------------------------------------------------------
__global__ void k_select(const float4* __restrict__ part,
                         const float* __restrict__ x,
                         const float* __restrict__ cb,
                         const float* __restrict__ c2,
                         float* __restrict__ out_idx_f,
                         int* __restrict__ idx_i,
                         int* __restrict__ used) {
    int wv   = threadIdx.x >> 6;
    int lane = threadIdx.x & 63;
    int row  = blockIdx.x * 4 + wv;
    float4 p = part[(size_t)row * 64 + lane];
    float s1 = p.x; int i1 = __float_as_int(p.y);
    float s2 = p.z; int i2 = __float_as_int(p.w);
    float gm = s1;
#pragma unroll
    for (int off = 1; off < 64; off <<= 1) gm = fminf(gm, __shfl_xor(gm, off, 64));
    float thresh = gm + 1.0f;
    unsigned long long m1 = __ballot(s1 <= thresh);
    unsigned long long m2 = __ballot(s2 <= thresh);
    float be = INFINITY; int bi = 0x7fffffff;
    const float4* xr = reinterpret_cast<const float4*>(x + (size_t)row * DIM);
    while (m1 | m2) {
        int vi;
        if (m1) { int t = __ffsll(m1) - 1; m1 &= m1 - 1; vi = __shfl(i1, t); }
        else    { int t = __ffsll(m2) - 1; m2 &= m2 - 1; vi = __shfl(i2, t); }
        const float4* cr = reinterpret_cast<const float4*>(cb + (size_t)vi * DIM);
        float d = 0.f;
#pragma unroll
        for (int q = 0; q < 2; ++q) {
            float4 a = xr[q * 64 + lane];
            float4 b = cr[q * 64 + lane];
            d += a.x * b.x + a.y * b.y + a.z * b.z + a.w * b.w;
        }
#pragma unroll
        for (int off = 1; off < 64; off <<= 1) d += __shfl_xor(d, off, 64);
        float se = c2[vi] - 2.f * d;
        if (se < be || (se == be && vi < bi)) { be = se; bi = vi; }
    }
    if (lane == 0) {
        out_idx_f[row] = (float)bi;
        idx_i[row]     = bi;
        used[bi]       = 1;
    }
}

__global__ void k_streak(const int* __restrict__ streak_in,
                         const int* __restrict__ used,
                         float* __restrict__ out) {
    int v = blockIdx.x * 256 + threadIdx.x;
    if (v < VOCAB) out[v] = used[v] ? 0.f : (float)(streak_in[v] + 1);
}

__global__ void k_gather(const float* __restrict__ cb,
                         const int* __restrict__ idx_i,
                         float* __restrict__ out) {
    size_t t  = (size_t)blockIdx.x * 256 + threadIdx.x;
    int    n  = (int)(t >> 7);
    int    d4 = (int)(t & 127);
    reinterpret_cast<float4*>(out)[t] =
        reinterpret_cast<const float4*>(cb + (size_t)idx_i[n] * DIM)[d4];
}

extern "C" void kernel_launch(void* const* d_in, const int* in_sizes, int n_in,
                              void* d_out, int out_size, void* d_ws, size_t ws_size,
                              hipStream_t stream) {
    const float* x      = (const float*)d_in[0];
    const float* cb     = (const float*)d_in[1];
    const int*   streak = (const int*)d_in[2];

    float* out       = (float*)d_out;
    float* out_embed = out;
    float* out_idx   = out + (size_t)N_ROWS * DIM;
    float* out_strk  = out_idx + N_ROWS;

    char* ws = (char*)d_ws;
    unsigned short* xhi  = (unsigned short*)(ws);                 // 16.8 MB
    unsigned short* cbhi = (unsigned short*)(ws + (32u << 20));   // 8.4 MB
    float* c2    = (float*)(ws + (48u << 20));                    // 32 KB
    int*   idx_i = (int*)(ws + (48u << 20) + (1u << 16));         // 64 KB
    int*   used  = (int*)(ws + (48u << 20) + (2u << 16));         // 32 KB
    float4* part = (float4*)(ws + (49u << 20));                   // 16.8 MB

    hipMemsetAsync(used, 0, VOCAB * sizeof(int), stream);
    k_split_hi<<<(N_ROWS * DIM / 4) / 256, 256, 0, stream>>>(x, xhi, N_ROWS * DIM / 4);
    k_split_cb<<<VOCAB / 4, 256, 0, stream>>>(cb, cbhi, c2);
    k_mfma8<<<2048, 512, 0, stream>>>(xhi, cbhi, c2, part);
    k_select<<<N_ROWS / 4, 256, 0, stream>>>(part, x, cb, c2, out_idx, idx_i, used);
    k_streak<<<VOCAB / 256, 256, 0, stream>>>(streak, used, out_strk);
    k_gather<<<(N_ROWS * DIM / 4) / 256, 256, 0, stream>>>(cb, idx_i, out_embed);
}

// Round 9
// 591.671 us; speedup vs baseline: 1.8932x; 1.8932x over previous
//
#include <hip/hip_runtime.h>
#include <hip/hip_bf16.h>
#include <math.h>

// Problem: input (16,1024,512) f32, codebook (8192,512) f32
#define N_ROWS 16384
#define DIM    512
#define VOCAB  8192

typedef __attribute__((ext_vector_type(8))) short short8;
typedef __attribute__((ext_vector_type(4))) float f32x4;

__device__ inline unsigned short f2bf(float f) {      // RNE f32 -> bf16 bits
    unsigned u = __float_as_uint(f);
    u += 0x7fff + ((u >> 16) & 1);
    return (unsigned short)(u >> 16);
}

__device__ inline void gload16(const void* g, void* l) {
    __builtin_amdgcn_global_load_lds(
        (const __attribute__((address_space(1))) void*)g,
        (__attribute__((address_space(3))) void*)l, 16, 0, 0);
}

__device__ inline void top2_ins(float s, int v, float& s1, int& i1, float& s2, int& i2) {
    if (s < s1 || (s == s1 && v < i1)) { s2 = s1; i2 = i1; s1 = s; i1 = v; }
    else if (s < s2 || (s == s2 && v < i2)) { s2 = s; i2 = v; }
}

// ---------------------------------------------------------------------------
// fp32 -> bf16 for input x
// ---------------------------------------------------------------------------
__global__ void k_split_hi(const float* __restrict__ in, unsigned short* __restrict__ hi,
                           int n4) {
    int t = blockIdx.x * 256 + threadIdx.x;
    if (t >= n4) return;
    float4 v = reinterpret_cast<const float4*>(in)[t];
    ushort4 h;
    h.x = f2bf(v.x); h.y = f2bf(v.y); h.z = f2bf(v.z); h.w = f2bf(v.w);
    reinterpret_cast<ushort4*>(hi)[t] = h;
}

// ---------------------------------------------------------------------------
// codebook: fp32 -> bf16 AND c2[v] = sum(cb[v]^2) in one pass (validated)
// ---------------------------------------------------------------------------
__global__ void k_split_cb(const float* __restrict__ cb, unsigned short* __restrict__ hi,
                           float* __restrict__ c2) {
    int row  = blockIdx.x * 4 + (threadIdx.x >> 6);
    int lane = threadIdx.x & 63;
    const float4* p = reinterpret_cast<const float4*>(cb + (size_t)row * DIM);
    float4 a = p[lane * 2], b = p[lane * 2 + 1];
    float s = a.x*a.x + a.y*a.y + a.z*a.z + a.w*a.w
            + b.x*b.x + b.y*b.y + b.z*b.z + b.w*b.w;
    short8 h;
    h[0] = f2bf(a.x); h[1] = f2bf(a.y); h[2] = f2bf(a.z); h[3] = f2bf(a.w);
    h[4] = f2bf(b.x); h[5] = f2bf(b.y); h[6] = f2bf(b.z); h[7] = f2bf(b.w);
    *reinterpret_cast<short8*>(hi + (size_t)row * DIM + lane * 8) = h;
#pragma unroll
    for (int off = 32; off > 0; off >>= 1) s += __shfl_xor(s, off, 64);
    if (lane == 0) c2[row] = s;
}

// ---------------------------------------------------------------------------
// bf16 MFMA GEMM (K=512) + fused per-tile top-2 argmin.
// Scale-up of the r5-VALIDATED 2-phase structure: 256x256 tile, BK=64,
// 1024 threads = 16 waves (4M x 4N), wave = 64 rows x 64 cols, acc[4][4].
// LDS 128 KiB: 2 dbuf x (A,B) x [256 rows][64 bf16], XOR slot swizzle
// (linear gload_lds dest + inverse-swizzled source + swizzled ds_read).
// Loop skeleton identical to r5: prefetch next tile, sched_barrier,
// ds_read+MFMA, vmcnt(0)+s_barrier.  Staging traffic 2.1 GB -> 1.07 GB,
// occupancy 8 -> 16 waves/CU vs r5.
// ---------------------------------------------------------------------------
__launch_bounds__(1024, 1)
__global__ void k_mfma_argmin(const unsigned short* __restrict__ xhi,
                              const unsigned short* __restrict__ cbhi,
                              const float* __restrict__ c2,
                              float4* __restrict__ part) {
    __shared__ __align__(16) char As[2 * 32768];   // [buf][256 rows][64 bf16]
    __shared__ __align__(16) char Bs[2 * 32768];
    const int tid  = threadIdx.x;
    const int w    = tid >> 6;            // 0..15
    const int wm   = w >> 2, wn = w & 3;  // 4M x 4N wave grid
    const int lane = tid & 63;
    const int l15  = lane & 15;
    const int lg   = lane >> 4;

    // XCD-aware swizzle (bijective: 2048 % 8 == 0), validated in r3/r8
    const int g  = blockIdx.x;
    const int wg = (g & 7) * 256 + (g >> 3);
    const int by = wg >> 5, bx = wg & 31;
    const int rowBase = by * 256;
    const int colBase = bx * 256;

    f32x4 acc[4][4];
#pragma unroll
    for (int mi = 0; mi < 4; ++mi)
#pragma unroll
        for (int nj = 0; nj < 4; ++nj) acc[mi][nj] = (f32x4)0.f;

    // staging: chunk = 1024B = 8 rows of 128B; 32 chunks per tile;
    // wave w stages chunks 2w, 2w+1 of A and of B.
    // source slot ^= row&7 (rule 21: swizzled source + linear dest).
    const int r8     = lane >> 3;
    const int srcoff = ((lane & 7) ^ r8) << 4;

#define STAGE(BUF, KT) do {                                                   \
    const int _kb = (KT) << 7;                                                \
    _Pragma("unroll") for (int _c = 0; _c < 2; ++_c) {                        \
        int _ch = 2 * w + _c;                                                 \
        gload16((const char*)xhi + (size_t)(rowBase + 8 * _ch + r8) * 1024 +  \
                    _kb + srcoff, As + (BUF) * 32768 + 1024 * _ch);           \
        gload16((const char*)cbhi + (size_t)(colBase + 8 * _ch + r8) * 1024 + \
                    _kb + srcoff, Bs + (BUF) * 32768 + 1024 * _ch);           \
    } } while (0)

    STAGE(0, 0);
    asm volatile("s_waitcnt vmcnt(0)" ::: "memory");
    asm volatile("s_barrier" ::: "memory");

    for (int kt = 0; kt < 8; ++kt) {               // 8 K-tiles of 64 = K 512
        const int cur = kt & 1;
        if (kt < 7) STAGE(cur ^ 1, kt + 1);        // prefetch next tile
        __builtin_amdgcn_sched_barrier(0);         // loads issue before compute
        const char* Ab = As + cur * 32768;
        const char* Bb = Bs + cur * 32768;
#pragma unroll
        for (int kk = 0; kk < 2; ++kk) {
            const int ob = kk * 64 + lg * 16;
            short8 a[4], b[4];
#pragma unroll
            for (int mi = 0; mi < 4; ++mi) {
                int r = wm * 64 + mi * 16 + l15;
                a[mi] = *(const short8*)(Ab + r * 128 + (ob ^ ((r & 7) << 4)));
            }
#pragma unroll
            for (int nj = 0; nj < 4; ++nj) {
                int r = wn * 64 + nj * 16 + l15;
                b[nj] = *(const short8*)(Bb + r * 128 + (ob ^ ((r & 7) << 4)));
            }
#pragma unroll
            for (int mi = 0; mi < 4; ++mi)
#pragma unroll
                for (int nj = 0; nj < 4; ++nj)
                    acc[mi][nj] = __builtin_amdgcn_mfma_f32_16x16x32_bf16(
                        a[mi], b[nj], acc[mi][nj], 0, 0, 0);
        }
        asm volatile("s_waitcnt vmcnt(0)" ::: "memory");  // prefetch landed
        asm volatile("s_barrier" ::: "memory");           // all waves done
    }

    // Epilogue: score = c2 - 2*acc; per-row top-2 per 64-col wave span,
    // then LDS merge of wn pairs -> per-128-col top-2 (part layout = r2/r5).
    // C frag: col = l15, row = 4*lg + reg.
    float c2v[4];
#pragma unroll
    for (int nj = 0; nj < 4; ++nj) c2v[nj] = c2[colBase + wn * 64 + nj * 16 + l15];

    float4* scr = (float4*)As;   // [256 rows][4 = wn], 16 KB, staging done
#pragma unroll
    for (int mi = 0; mi < 4; ++mi) {
#pragma unroll
        for (int r = 0; r < 4; ++r) {
            float s1 = INFINITY, s2 = INFINITY;
            int   i1 = 0x7fffffff, i2 = 0x7fffffff;
#pragma unroll
            for (int nj = 0; nj < 4; ++nj) {
                float sc = fmaf(-2.f, acc[mi][nj][r], c2v[nj]);
                int   v  = colBase + wn * 64 + nj * 16 + l15;
                top2_ins(sc, v, s1, i1, s2, i2);
            }
#pragma unroll
            for (int off = 1; off < 16; off <<= 1) {   // butterfly, 16 col-lanes
                float t1 = __shfl_xor(s1, off, 64); int j1 = __shfl_xor(i1, off, 64);
                float t2 = __shfl_xor(s2, off, 64); int j2 = __shfl_xor(i2, off, 64);
                bool bf = (t1 < s1) || (t1 == s1 && j1 < i1);
                if (bf) {
                    float ns; int ni;
                    if (s1 < t2 || (s1 == t2 && i1 < j2)) { ns = s1; ni = i1; }
                    else                                   { ns = t2; ni = j2; }
                    s1 = t1; i1 = j1; s2 = ns; i2 = ni;
                } else if (t1 < s2 || (t1 == s2 && j1 < i2)) { s2 = t1; i2 = j1; }
            }
            if (l15 == 0)
                scr[(wm * 64 + mi * 16 + 4 * lg + r) * 4 + wn] =
                    make_float4(s1, __int_as_float(i1), s2, __int_as_float(i2));
        }
    }
    __syncthreads();
    if (tid < 512) {   // row = tid>>1, half = tid&1 -> merge wn pair {2h,2h+1}
        int row = tid >> 1, h = tid & 1;
        float s1 = INFINITY, s2 = INFINITY;
        int   i1 = 0x7fffffff, i2 = 0x7fffffff;
#pragma unroll
        for (int q = 0; q < 2; ++q) {
            float4 p = scr[row * 4 + h * 2 + q];
            top2_ins(p.x, __float_as_int(p.y), s1, i1, s2, i2);
            top2_ins(p.z, __float_as_int(p.w), s1, i1, s2, i2);
        }
        part[(size_t)(rowBase + row) * 64 + bx * 2 + h] =
            make_float4(s1, __int_as_float(i1), s2, __int_as_float(i2));
    }
}

// ---------------------------------------------------------------------------
// Per-row final: approx global min over 64 per-128-col top2s; exact fp32
// rescore of all candidates within min+1.0 (>14 sigma of bf16 approx error);
// lexicographic (score, idx) min == reference argmin semantics.
// ---------------------------------------------------------------------------
__global__ void k_select(const float4* __restrict__ part,
                         const float* __restrict__ x,
                         const float* __restrict__ cb,
                         const float* __restrict__ c2,
                         float* __restrict__ out_idx_f,
                         int* __restrict__ idx_i,
                         int* __restrict__ used) {
    int wv   = threadIdx.x >> 6;
    int lane = threadIdx.x & 63;
    int row  = blockIdx.x * 4 + wv;
    float4 p = part[(size_t)row * 64 + lane];
    float s1 = p.x; int i1 = __float_as_int(p.y);
    float s2 = p.z; int i2 = __float_as_int(p.w);
    float gm = s1;
#pragma unroll
    for (int off = 1; off < 64; off <<= 1) gm = fminf(gm, __shfl_xor(gm, off, 64));
    float thresh = gm + 1.0f;
    unsigned long long m1 = __ballot(s1 <= thresh);
    unsigned long long m2 = __ballot(s2 <= thresh);
    float be = INFINITY; int bi = 0x7fffffff;
    const float4* xr = reinterpret_cast<const float4*>(x + (size_t)row * DIM);
    while (m1 | m2) {
        int vi;
        if (m1) { int t = __ffsll(m1) - 1; m1 &= m1 - 1; vi = __shfl(i1, t); }
        else    { int t = __ffsll(m2) - 1; m2 &= m2 - 1; vi = __shfl(i2, t); }
        const float4* cr = reinterpret_cast<const float4*>(cb + (size_t)vi * DIM);
        float d = 0.f;
#pragma unroll
        for (int q = 0; q < 2; ++q) {
            float4 a = xr[q * 64 + lane];
            float4 b = cr[q * 64 + lane];
            d += a.x * b.x + a.y * b.y + a.z * b.z + a.w * b.w;
        }
#pragma unroll
        for (int off = 1; off < 64; off <<= 1) d += __shfl_xor(d, off, 64);
        float se = c2[vi] - 2.f * d;
        if (se < be || (se == be && vi < bi)) { be = se; bi = vi; }
    }
    if (lane == 0) {
        out_idx_f[row] = (float)bi;
        idx_i[row]     = bi;
        used[bi]       = 1;
    }
}

__global__ void k_streak(const int* __restrict__ streak_in,
                         const int* __restrict__ used,
                         float* __restrict__ out) {
    int v = blockIdx.x * 256 + threadIdx.x;
    if (v < VOCAB) out[v] = used[v] ? 0.f : (float)(streak_in[v] + 1);
}

__global__ void k_gather(const float* __restrict__ cb,
                         const int* __restrict__ idx_i,
                         float* __restrict__ out) {
    size_t t  = (size_t)blockIdx.x * 256 + threadIdx.x;
    int    n  = (int)(t >> 7);
    int    d4 = (int)(t & 127);
    reinterpret_cast<float4*>(out)[t] =
        reinterpret_cast<const float4*>(cb + (size_t)idx_i[n] * DIM)[d4];
}

extern "C" void kernel_launch(void* const* d_in, const int* in_sizes, int n_in,
                              void* d_out, int out_size, void* d_ws, size_t ws_size,
                              hipStream_t stream) {
    const float* x      = (const float*)d_in[0];
    const float* cb     = (const float*)d_in[1];
    const int*   streak = (const int*)d_in[2];

    float* out       = (float*)d_out;
    float* out_embed = out;
    float* out_idx   = out + (size_t)N_ROWS * DIM;
    float* out_strk  = out_idx + N_ROWS;

    char* ws = (char*)d_ws;
    unsigned short* xhi  = (unsigned short*)(ws);                 // 16.8 MB
    unsigned short* cbhi = (unsigned short*)(ws + (32u << 20));   // 8.4 MB
    float* c2    = (float*)(ws + (48u << 20));                    // 32 KB
    int*   idx_i = (int*)(ws + (48u << 20) + (1u << 16));         // 64 KB
    int*   used  = (int*)(ws + (48u << 20) + (2u << 16));         // 32 KB
    float4* part = (float4*)(ws + (49u << 20));                   // 16.8 MB

    hipMemsetAsync(used, 0, VOCAB * sizeof(int), stream);
    k_split_hi<<<(N_ROWS * DIM / 4) / 256, 256, 0, stream>>>(x, xhi, N_ROWS * DIM / 4);
    k_split_cb<<<VOCAB / 4, 256, 0, stream>>>(cb, cbhi, c2);
    k_mfma_argmin<<<2048, 1024, 0, stream>>>(xhi, cbhi, c2, part);
    k_select<<<N_ROWS / 4, 256, 0, stream>>>(part, x, cb, c2, out_idx, idx_i, used);
    k_streak<<<VOCAB / 256, 256, 0, stream>>>(streak, used, out_strk);
    k_gather<<<(N_ROWS * DIM / 4) / 256, 256, 0, stream>>>(cb, idx_i, out_embed);
}